// Round 3
// baseline (620.501 us; speedup 1.0000x reference)
//
#include <hip/hip_runtime.h>
#include <math.h>

#define C_ 128
#define MID 8
#define CS 262144            // channel stride = 64*64*64 floats
#define SQRT8 2.8284271247461903f   // 2*sqrt(2)
#define NBLK_GAP 2048

typedef float vf4 __attribute__((ext_vector_type(4)));  // native vector for
                                                        // nontemporal builtins

static __device__ __forceinline__ float sigmoidf_(float z) {
    return 1.0f / (1.0f + __expf(-z));
}

// ---------------------------------------------------------------------------
// K1 (fused K1+K2): gap partial sums, last-block-done global MLP.
// grid 2048 = (b, c, g) with g = dc/4. Each block sums the raw corners of
// its 4-dc slab -> partial[blk] (release store), bumps the done counter;
// the last block reduces all 2048 partials -> gap, runs the global
// 128->8->128 MLP, folds lb2, writes gbias[b*128+c].
// ---------------------------------------------------------------------------
__global__ __launch_bounds__(256) void gap_kernel(
    const float* __restrict__ x,
    const float* __restrict__ gw1, const float* __restrict__ gb1,
    const float* __restrict__ gw2, const float* __restrict__ gb2,
    const float* __restrict__ lb2,
    float* __restrict__ partial,       // [2048]
    unsigned int* __restrict__ done,   // [1], memset to 0 pre-launch
    float* __restrict__ gbias)         // [2][128]
{
    __shared__ float red[4];
    __shared__ int amLast;
    __shared__ float sgap[2][C_];
    __shared__ float shid[2][MID];

    const int blk = blockIdx.x;          // b*1024 + c*8 + g
    const int g = blk & 7;
    const int c = (blk >> 3) & 127;
    const int b = blk >> 10;
    const int tid = threadIdx.x;
    const int f = tid & 15;

    const float* xb = x + (size_t)(b * C_ + c) * CS;
    float s = 0.0f;
    #pragma unroll
    for (int k = 0; k < 8; ++k) {
        const int r   = (tid >> 4) + 16 * k;   // 0..127
        const int dcl = r >> 5;                // 0..3
        const int hc  = r & 31;
        const vf4 v = ((const vf4*)(
            xb + (size_t)(2 * (4 * g + dcl)) * 4096 + (size_t)(2 * hc) * 64))[f];
        s += v.x + v.z;
    }
    s += __shfl_down(s, 32);
    s += __shfl_down(s, 16);
    s += __shfl_down(s, 8);
    s += __shfl_down(s, 4);
    s += __shfl_down(s, 2);
    s += __shfl_down(s, 1);
    if ((tid & 63) == 0) red[tid >> 6] = s;
    __syncthreads();
    if (tid == 0) {
        const float v = red[0] + red[1] + red[2] + red[3];
        __hip_atomic_store(&partial[blk], v, __ATOMIC_RELEASE,
                           __HIP_MEMORY_SCOPE_AGENT);
        const unsigned int prev = __hip_atomic_fetch_add(
            done, 1u, __ATOMIC_ACQ_REL, __HIP_MEMORY_SCOPE_AGENT);
        amLast = (prev == NBLK_GAP - 1);
    }
    __syncthreads();
    if (!amLast) return;

    // ---- last block: reduce partials -> gap, global MLP ----
    const int t = tid;                 // 256 threads = (b, c)
    const int bb = t >> 7, cc = t & 127;
    {
        float tot = 0.0f;
        #pragma unroll
        for (int j = 0; j < 8; ++j)
            tot += __hip_atomic_load(&partial[(size_t)t * 8 + j],
                                     __ATOMIC_RELAXED, __HIP_MEMORY_SCOPE_AGENT);
        sgap[bb][cc] = tot * (SQRT8 / 32768.0f);
    }
    __syncthreads();
    if (t < 16) {
        const int b2 = t >> 3, m = t & 7;
        float a = gb1[m];
        for (int k = 0; k < C_; ++k) a += gw1[m * C_ + k] * sgap[b2][k];
        shid[b2][m] = fmaxf(a, 0.0f);
    }
    __syncthreads();
    float a = gb2[cc] + lb2[cc];
    #pragma unroll
    for (int m = 0; m < MID; ++m) a += gw2[cc * MID + m] * shid[bb][m];
    gbias[t] = a;
}

// ---------------------------------------------------------------------------
// K3: fused local-MLP + blend, software-pipelined. grid 4096 =
// (b, dc, hc, w-half); each block owns all 128 channels of one coarse cell.
// Phase 1: load corner rows (registers + xs staging), then ISSUE the k=0
//          off-corner prefetch before the barriers so HBM latency hides
//          under the hidden-MLP phase.
// Phase 2: hidden[8][16] = relu(lw1 @ x_sum + lb1).
// Phase 3: per k: consume prefetched rows, issue k+1 prefetch, gate+blend.
// Off-corner loads and all stores are nontemporal (touched exactly once) so
// K1's corner lines survive in L3 for the phase-1 re-read.
// ---------------------------------------------------------------------------
__global__ __launch_bounds__(256) void fused_blend_kernel(
    const float* __restrict__ x,
    const float* __restrict__ lw1, const float* __restrict__ lb1,
    const float* __restrict__ lw2,
    const float* __restrict__ gbias,
    float* __restrict__ out)
{
    __shared__ float xs[C_ * 17];     // x_sum[c][wc_local], stride 17
    __shared__ float shid[MID * 16];  // hidden[m][wc_local]
    __shared__ float s1T[C_ * MID];   // lw1 transposed: [cc][m]
    __shared__ float s2T[MID * C_];   // lw2 transposed: [m][c]
    __shared__ float sgb[C_];

    const int blk = blockIdx.x;        // b*2048 + dc*64 + hc*2 + wh
    const int wh  = blk & 1;
    const int hc  = (blk >> 1) & 31;
    const int dc  = (blk >> 6) & 31;
    const int b   = blk >> 11;
    const int tid = threadIdx.x;
    const int f   = tid & 7;           // float4 index within 32-float half-row
    const int c0  = tid >> 3;          // 0..31

    for (int i = tid; i < MID * C_; i += 256) {
        s1T[i] = lw1[(i & 7) * C_ + (i >> 3)];      // s1T[cc*8+m] = lw1[m][cc]
        s2T[i] = lw2[(i & 127) * MID + (i >> 7)];   // s2T[m*128+c] = lw2[c][m]
    }
    if (tid < C_) sgb[tid] = gbias[b * C_ + tid];

    const float* xb = x + (size_t)b * C_ * CS
                    + (size_t)(2 * dc) * 4096 + (size_t)(2 * hc) * 64 + wh * 32;

    vf4 r00[4];
    #pragma unroll
    for (int k = 0; k < 4; ++k) {
        const int c = c0 + 32 * k;
        const vf4 v = ((const vf4*)(xb + (size_t)c * CS))[f];
        r00[k] = v;
        xs[c * 17 + 2 * f]     = SQRT8 * v.x;
        xs[c * 17 + 2 * f + 1] = SQRT8 * v.z;
    }

    // prefetch k=0's off-corner rows now: latency hides under phase 2
    const size_t coff0 = (size_t)c0 * CS;
    vf4 p01 = __builtin_nontemporal_load((const vf4*)(xb + coff0 + 64) + f);
    vf4 p10 = __builtin_nontemporal_load((const vf4*)(xb + coff0 + 4096) + f);
    vf4 p11 = __builtin_nontemporal_load((const vf4*)(xb + coff0 + 4160) + f);

    __syncthreads();

    if (tid < 128) {
        const int m = tid >> 4, wc = tid & 15;
        float a = lb1[m];
        for (int cc = 0; cc < C_; ++cc) a += s1T[cc * MID + m] * xs[cc * 17 + wc];
        shid[m * 16 + wc] = fmaxf(a, 0.0f);
    }
    __syncthreads();

    float* ob = out + (xb - x);
    #pragma unroll
    for (int k = 0; k < 4; ++k) {
        const int c = c0 + 32 * k;
        const size_t coff = (size_t)c * CS;

        const vf4 a00 = r00[k];
        const vf4 a01 = p01;
        const vf4 a10 = p10;
        const vf4 a11 = p11;

        if (k < 3) {   // issue k+1 prefetch before consuming k
            const size_t cn = (size_t)(c + 32) * CS;
            p01 = __builtin_nontemporal_load((const vf4*)(xb + cn + 64) + f);
            p10 = __builtin_nontemporal_load((const vf4*)(xb + cn + 4096) + f);
            p11 = __builtin_nontemporal_load((const vf4*)(xb + cn + 4160) + f);
        }

        float d0 = sgb[c], d1 = sgb[c];
        #pragma unroll
        for (int m = 0; m < MID; ++m) {
            const float wv = s2T[m * C_ + c];
            d0 += wv * shid[m * 16 + 2 * f];
            d1 += wv * shid[m * 16 + 2 * f + 1];
        }
        const float w0 = sigmoidf_(d0);
        const float w1 = sigmoidf_(d1);

        const float mean0 = (a00.x + a00.y + a01.x + a01.y +
                             a10.x + a10.y + a11.x + a11.y) * 0.125f;
        const float mean1 = (a00.z + a00.w + a01.z + a01.w +
                             a10.z + a10.w + a11.z + a11.w) * 0.125f;
        const float om0 = (1.0f - w0) * mean0;
        const float om1 = (1.0f - w1) * mean1;

        vf4 o;
        o.x = w0 * a00.x + om0; o.y = w0 * a00.y + om0;
        o.z = w1 * a00.z + om1; o.w = w1 * a00.w + om1;
        __builtin_nontemporal_store(o, (vf4*)(ob + coff) + f);
        o.x = w0 * a01.x + om0; o.y = w0 * a01.y + om0;
        o.z = w1 * a01.z + om1; o.w = w1 * a01.w + om1;
        __builtin_nontemporal_store(o, (vf4*)(ob + coff + 64) + f);
        o.x = w0 * a10.x + om0; o.y = w0 * a10.y + om0;
        o.z = w1 * a10.z + om1; o.w = w1 * a10.w + om1;
        __builtin_nontemporal_store(o, (vf4*)(ob + coff + 4096) + f);
        o.x = w0 * a11.x + om0; o.y = w0 * a11.y + om0;
        o.z = w1 * a11.z + om1; o.w = w1 * a11.w + om1;
        __builtin_nontemporal_store(o, (vf4*)(ob + coff + 4160) + f);
    }
}

extern "C" void kernel_launch(void* const* d_in, const int* in_sizes, int n_in,
                              void* d_out, int out_size, void* d_ws, size_t ws_size,
                              hipStream_t stream) {
    const float* x   = (const float*)d_in[0];
    const float* gw1 = (const float*)d_in[1];
    const float* gb1 = (const float*)d_in[2];
    const float* gw2 = (const float*)d_in[3];
    const float* gb2 = (const float*)d_in[4];
    const float* lw1 = (const float*)d_in[5];
    const float* lb1 = (const float*)d_in[6];
    const float* lw2 = (const float*)d_in[7];
    const float* lb2 = (const float*)d_in[8];
    float* o  = (float*)d_out;
    float* ws = (float*)d_ws;

    float* partial     = ws;                          // 2048 floats
    float* gbias       = ws + 2048;                   // 256 floats
    unsigned int* done = (unsigned int*)(ws + 2304);  // 1 uint

    (void)hipMemsetAsync(done, 0, sizeof(unsigned int), stream);
    gap_kernel<<<NBLK_GAP, 256, 0, stream>>>(x, gw1, gb1, gw2, gb2, lb2,
                                             partial, done, gbias);
    fused_blend_kernel<<<4096, 256, 0, stream>>>(x, lw1, lb1, lw2, gbias, o);
}

// Round 5
// 467.499 us; speedup vs baseline: 1.3273x; 1.3273x over previous
//
#include <hip/hip_runtime.h>
#include <math.h>

#define C_ 128
#define MID 8
#define CS 262144            // channel stride = 64*64*64 floats
#define SQRT8 2.8284271247461903f   // 2*sqrt(2)

typedef float vf4 __attribute__((ext_vector_type(4)));  // native vector for
                                                        // nontemporal builtins

static __device__ __forceinline__ float sigmoidf_(float z) {
    return 1.0f / (1.0f + __expf(-z));
}

// ---------------------------------------------------------------------------
// K1: gap partial sums only. grid 2048 = (b, c, g) with g = dc/4.
// Each block sums the raw corners (v.x + v.z of the even-d/even-h rows) of
// its 4-dc slab and writes ONE float. Plain store — no atomics, no
// cross-block coordination (round-3 lesson: same-address agent-scope
// atomics serialize at ~90 ns each = 185 us for 2048 blocks).
// ---------------------------------------------------------------------------
__global__ __launch_bounds__(256) void gap_partial_kernel(
    const float* __restrict__ x,
    float* __restrict__ partial)    // [2048] : [b][c][g]
{
    __shared__ float red[4];
    const int blk = blockIdx.x;          // b*1024 + c*8 + g
    const int g = blk & 7;
    const int c = (blk >> 3) & 127;
    const int b = blk >> 10;
    const int tid = threadIdx.x;
    const int f = tid & 15;

    const float* xb = x + (size_t)(b * C_ + c) * CS;
    float s = 0.0f;
    #pragma unroll
    for (int k = 0; k < 8; ++k) {
        const int r   = (tid >> 4) + 16 * k;   // 0..127
        const int dcl = r >> 5;                // 0..3
        const int hc  = r & 31;
        const vf4 v = ((const vf4*)(
            xb + (size_t)(2 * (4 * g + dcl)) * 4096 + (size_t)(2 * hc) * 64))[f];
        s += v.x + v.z;
    }
    s += __shfl_down(s, 32);
    s += __shfl_down(s, 16);
    s += __shfl_down(s, 8);
    s += __shfl_down(s, 4);
    s += __shfl_down(s, 2);
    s += __shfl_down(s, 1);
    if ((tid & 63) == 0) red[tid >> 6] = s;
    __syncthreads();
    if (tid == 0) partial[blk] = red[0] + red[1] + red[2] + red[3];
}

// ---------------------------------------------------------------------------
// K2: one block, 256 threads = (b, c). Reduce 8 partials per (b,c) -> gap,
// global MLP 128->8->128, fold lb2: gbias[b*128+c] = gout + lb2.
// ~4 us dispatch; cheap and safe (vs the 185 us atomic fusion of round 3).
// ---------------------------------------------------------------------------
__global__ __launch_bounds__(256) void gmlp_kernel(
    const float* __restrict__ partial,
    const float* __restrict__ gw1, const float* __restrict__ gb1,
    const float* __restrict__ gw2, const float* __restrict__ gb2,
    const float* __restrict__ lb2,
    float* __restrict__ gbias)      // [2][128]
{
    __shared__ float sgap[2][C_];
    __shared__ float shid[2][MID];
    const int t = threadIdx.x;
    const int b = t >> 7, c = t & 127;
    {
        const vf4* p = (const vf4*)(partial + (size_t)t * 8);
        const vf4 a = p[0], d = p[1];
        sgap[b][c] = (a.x + a.y + a.z + a.w + d.x + d.y + d.z + d.w)
                     * (SQRT8 / 32768.0f);
    }
    __syncthreads();
    if (t < 16) {
        const int bb = t >> 3, m = t & 7;
        float a = gb1[m];
        for (int cc = 0; cc < C_; ++cc) a += gw1[m * C_ + cc] * sgap[bb][cc];
        shid[bb][m] = fmaxf(a, 0.0f);
    }
    __syncthreads();
    float a = gb2[c] + lb2[c];
    #pragma unroll
    for (int m = 0; m < MID; ++m) a += gw2[c * MID + m] * shid[b][m];
    gbias[t] = a;
}

// ---------------------------------------------------------------------------
// K3: fused local-MLP + blend, software-pipelined. grid 4096 =
// (b, dc, hc, w-half); each block owns all 128 channels of one coarse cell.
// Phase 1: load corner rows (registers + xs staging), issue k=0 off-corner
//          prefetch so HBM latency hides under the hidden-MLP phase.
// Phase 2: hidden[8][16] = relu(lw1 @ x_sum + lb1).
// Phase 3: per k: consume prefetched rows, issue k+1 prefetch, gate+blend.
// Off-corner loads and all stores nontemporal (touched exactly once) so
// corner lines survive in L3 for the next iteration's gap read.
// ---------------------------------------------------------------------------
__global__ __launch_bounds__(256) void fused_blend_kernel(
    const float* __restrict__ x,
    const float* __restrict__ lw1, const float* __restrict__ lb1,
    const float* __restrict__ lw2,
    const float* __restrict__ gbias,
    float* __restrict__ out)
{
    __shared__ float xs[C_ * 17];     // x_sum[c][wc_local], stride 17
    __shared__ float shid[MID * 16];  // hidden[m][wc_local]
    __shared__ float s1T[C_ * MID];   // lw1 transposed: [cc][m]
    __shared__ float s2T[MID * C_];   // lw2 transposed: [m][c]
    __shared__ float sgb[C_];

    const int blk = blockIdx.x;        // b*2048 + dc*64 + hc*2 + wh
    const int wh  = blk & 1;
    const int hc  = (blk >> 1) & 31;
    const int dc  = (blk >> 6) & 31;
    const int b   = blk >> 11;
    const int tid = threadIdx.x;
    const int f   = tid & 7;           // float4 index within 32-float half-row
    const int c0  = tid >> 3;          // 0..31

    for (int i = tid; i < MID * C_; i += 256) {
        s1T[i] = lw1[(i & 7) * C_ + (i >> 3)];      // s1T[cc*8+m] = lw1[m][cc]
        s2T[i] = lw2[(i & 127) * MID + (i >> 7)];   // s2T[m*128+c] = lw2[c][m]
    }
    if (tid < C_) sgb[tid] = gbias[b * C_ + tid];

    const float* xb = x + (size_t)b * C_ * CS
                    + (size_t)(2 * dc) * 4096 + (size_t)(2 * hc) * 64 + wh * 32;

    vf4 r00[4];
    #pragma unroll
    for (int k = 0; k < 4; ++k) {
        const int c = c0 + 32 * k;
        const vf4 v = ((const vf4*)(xb + (size_t)c * CS))[f];
        r00[k] = v;
        xs[c * 17 + 2 * f]     = SQRT8 * v.x;
        xs[c * 17 + 2 * f + 1] = SQRT8 * v.z;
    }

    // prefetch k=0's off-corner rows now: latency hides under phase 2
    const size_t coff0 = (size_t)c0 * CS;
    vf4 p01 = __builtin_nontemporal_load((const vf4*)(xb + coff0 + 64) + f);
    vf4 p10 = __builtin_nontemporal_load((const vf4*)(xb + coff0 + 4096) + f);
    vf4 p11 = __builtin_nontemporal_load((const vf4*)(xb + coff0 + 4160) + f);

    __syncthreads();

    if (tid < 128) {
        const int m = tid >> 4, wc = tid & 15;
        float a = lb1[m];
        for (int cc = 0; cc < C_; ++cc) a += s1T[cc * MID + m] * xs[cc * 17 + wc];
        shid[m * 16 + wc] = fmaxf(a, 0.0f);
    }
    __syncthreads();

    float* ob = out + (xb - x);
    #pragma unroll
    for (int k = 0; k < 4; ++k) {
        const int c = c0 + 32 * k;
        const size_t coff = (size_t)c * CS;

        const vf4 a00 = r00[k];
        const vf4 a01 = p01;
        const vf4 a10 = p10;
        const vf4 a11 = p11;

        if (k < 3) {   // issue k+1 prefetch before consuming k
            const size_t cn = (size_t)(c + 32) * CS;
            p01 = __builtin_nontemporal_load((const vf4*)(xb + cn + 64) + f);
            p10 = __builtin_nontemporal_load((const vf4*)(xb + cn + 4096) + f);
            p11 = __builtin_nontemporal_load((const vf4*)(xb + cn + 4160) + f);
        }

        float d0 = sgb[c], d1 = sgb[c];
        #pragma unroll
        for (int m = 0; m < MID; ++m) {
            const float wv = s2T[m * C_ + c];
            d0 += wv * shid[m * 16 + 2 * f];
            d1 += wv * shid[m * 16 + 2 * f + 1];
        }
        const float w0 = sigmoidf_(d0);
        const float w1 = sigmoidf_(d1);

        const float mean0 = (a00.x + a00.y + a01.x + a01.y +
                             a10.x + a10.y + a11.x + a11.y) * 0.125f;
        const float mean1 = (a00.z + a00.w + a01.z + a01.w +
                             a10.z + a10.w + a11.z + a11.w) * 0.125f;
        const float om0 = (1.0f - w0) * mean0;
        const float om1 = (1.0f - w1) * mean1;

        vf4 o;
        o.x = w0 * a00.x + om0; o.y = w0 * a00.y + om0;
        o.z = w1 * a00.z + om1; o.w = w1 * a00.w + om1;
        __builtin_nontemporal_store(o, (vf4*)(ob + coff) + f);
        o.x = w0 * a01.x + om0; o.y = w0 * a01.y + om0;
        o.z = w1 * a01.z + om1; o.w = w1 * a01.w + om1;
        __builtin_nontemporal_store(o, (vf4*)(ob + coff + 64) + f);
        o.x = w0 * a10.x + om0; o.y = w0 * a10.y + om0;
        o.z = w1 * a10.z + om1; o.w = w1 * a10.w + om1;
        __builtin_nontemporal_store(o, (vf4*)(ob + coff + 4096) + f);
        o.x = w0 * a11.x + om0; o.y = w0 * a11.y + om0;
        o.z = w1 * a11.z + om1; o.w = w1 * a11.w + om1;
        __builtin_nontemporal_store(o, (vf4*)(ob + coff + 4160) + f);
    }
}

extern "C" void kernel_launch(void* const* d_in, const int* in_sizes, int n_in,
                              void* d_out, int out_size, void* d_ws, size_t ws_size,
                              hipStream_t stream) {
    const float* x   = (const float*)d_in[0];
    const float* gw1 = (const float*)d_in[1];
    const float* gb1 = (const float*)d_in[2];
    const float* gw2 = (const float*)d_in[3];
    const float* gb2 = (const float*)d_in[4];
    const float* lw1 = (const float*)d_in[5];
    const float* lb1 = (const float*)d_in[6];
    const float* lw2 = (const float*)d_in[7];
    const float* lb2 = (const float*)d_in[8];
    float* o  = (float*)d_out;
    float* ws = (float*)d_ws;

    float* partial = ws;           // 2048 floats : [b][c][g]
    float* gbias   = ws + 2048;    // 256 floats

    gap_partial_kernel<<<2048, 256, 0, stream>>>(x, partial);
    gmlp_kernel<<<1, 256, 0, stream>>>(partial, gw1, gb1, gw2, gb2, lb2, gbias);
    fused_blend_kernel<<<4096, 256, 0, stream>>>(x, lw1, lb1, lw2, gbias, o);
}